// Round 19
// baseline (274.114 us; speedup 1.0000x reference)
//
#include <hip/hip_runtime.h>

#define N_N 50000
#define N_E 800000
#define NG  128
#define NBKT 782          // ceil(50000/64) buckets of 64 nodes
#define CAP  1536         // slot capacity per bucket (8-padded mean ~1248, sigma ~37)
#define EPB  4096         // edges per k_bin block
#define BINB 196          // ceil(800000/4096)

typedef float4 f4;
typedef __attribute__((ext_vector_type(8))) short bf16x8;
typedef __attribute__((ext_vector_type(4))) float f32x4;

__device__ __forceinline__ unsigned short f2b(float x){
  unsigned int u = __float_as_uint(x);
  u += 0x7fffu + ((u >> 16) & 1u);
  return (unsigned short)(u >> 16);
}
__device__ __forceinline__ float b2f(unsigned short h){
  return __uint_as_float(((unsigned int)h) << 16);
}
__device__ __forceinline__ float2 b2f2(unsigned int u){
  float2 r;
  r.x = __uint_as_float(u << 16);
  r.y = __uint_as_float(u & 0xffff0000u);
  return r;
}

// ---------------- init: Wt transpose-cast (bid<128) + zero bcnt|gsum|gcnt (middle) + sentinels (last) ----------------
__global__ __launch_bounds__(256) void k_init(const float* __restrict__ W1, const float* __restrict__ W2,
    unsigned short* __restrict__ Wt1, unsigned short* __restrict__ Wt2,
    int* __restrict__ zp, int n4, unsigned int* __restrict__ x0z, unsigned int* __restrict__ x1z){
  int bid = blockIdx.x, t = threadIdx.x;
  int i = bid*256 + t;
  if (bid < 128){
    const float* W = (i < 16384) ? W1 : W2;
    unsigned short* Wt = (i < 16384) ? Wt1 : Wt2;
    int j = i & 16383;
    int k = j >> 7, n = j & 127;
    Wt[n*128 + k] = f2b(W[k*128 + n]);
  } else if (bid == gridDim.x - 1){
    if (t < 64)       x0z[(size_t)N_N*64 + t] = 0;        // sentinel row of xb0
    else if (t < 128) x1z[(size_t)N_N*64 + (t-64)] = 0;   // sentinel row of xb1
  } else {
    int z = i - 128*256;
    if (z < n4) zp[z] = 0;
  }
}

// ---------------- block-local counting sort into coarse buckets + gcnt count ----------------
__global__ __launch_bounds__(512) void k_bin(const int* __restrict__ ei,
    int* __restrict__ bcnt, unsigned int* __restrict__ bins,
    const int* __restrict__ batch, float* __restrict__ gcnt){
  __shared__ unsigned int sorted[EPB];   // 16 KB
  __shared__ int hist[NBKT];
  __shared__ int lstart[NBKT];
  __shared__ int lcur[NBKT];
  __shared__ int gbase[NBKT];
  __shared__ int segsum[16];
  int t = threadIdx.x;
  // gcnt: sorted batch -> wave-uniform atomics, coalesced by HW/compiler
  int gi = blockIdx.x*512 + t;
  if (gi < N_N) atomicAdd(&gcnt[batch[gi]], 1.0f);
  int e0 = blockIdx.x * EPB;
  int n = N_E - e0; if (n > EPB) n = EPB;
  for (int i=t; i<NBKT; i+=512) hist[i] = 0;
  __syncthreads();
  for (int i=t; i<n; i+=512){
    int d = ei[N_E + e0 + i];
    atomicAdd(&hist[d>>6], 1);
  }
  __syncthreads();
  int w = t >> 6, lane = t & 63;
  for (int seg = w; seg < 13; seg += 8){
    int idx = seg*64 + lane;
    int v = (idx < NBKT) ? hist[idx] : 0;
    int x = v;
    #pragma unroll
    for (int dd=1; dd<64; dd<<=1){ int y = __shfl_up(x, dd, 64); if (lane >= dd) x += y; }
    if (idx < NBKT) lstart[idx] = x - v;
    if (lane == 63) segsum[seg] = x;
  }
  __syncthreads();
  if (t == 0){ int s=0; for (int j=0;j<13;j++){ int v=segsum[j]; segsum[j]=s; s+=v; } }
  __syncthreads();
  for (int i=t; i<NBKT; i+=512){ int v = lstart[i] + segsum[i>>6]; lstart[i] = v; lcur[i] = v; }
  __syncthreads();
  for (int i=t; i<n; i+=512){
    int s = ei[e0 + i], d = ei[N_E + e0 + i];
    int pos = atomicAdd(&lcur[d>>6], 1);
    sorted[pos] = ((unsigned int)s << 16) | (unsigned int)d;
  }
  __syncthreads();
  for (int i=t; i<NBKT; i+=512) gbase[i] = atomicAdd(&bcnt[i], hist[i]);
  __syncthreads();
  for (int i=t; i<n; i+=512){
    unsigned int item = sorted[i];
    int d = item & 0xffff;
    int b = d >> 6;
    bins[b*CAP + gbase[b] + (i - lstart[b])] = item;
  }
}

// ---------------- fused: per-bucket CSR finalize (8-padded) + preprocess MLP, out = x1*dinv (bf16) ----------------
__global__ __launch_bounds__(256) void k_csrpre(const unsigned int* __restrict__ bins,
    const int* __restrict__ bcnt, int2* __restrict__ sd, float* __restrict__ dinv,
    int* __restrict__ ssrc,
    const float* __restrict__ emb, const float* __restrict__ pose,
    const float* __restrict__ W, const float* __restrict__ bias, unsigned short* __restrict__ out){
  __shared__ float As[64*64];
  __shared__ float Bs[64*128];
  __shared__ int hist[64];
  __shared__ int lcur[64];
  __shared__ float sdv[64];
  __shared__ int cnt_s;
  int b = blockIdx.x, t = threadIdx.x;

  // ---- CSR phase ----
  if (t < 64) hist[t] = 0;
  if (t == 0) cnt_s = bcnt[b];
  __syncthreads();
  int cnt = cnt_s;
  const unsigned int* P = bins + b*CAP;
  for (int j=t; j<cnt; j+=256) atomicAdd(&hist[P[j] & 63], 1);
  __syncthreads();
  if (t < 64){
    int v = hist[t];
    int ph = (v + 7) & ~7;               // padded to multiple of 8
    int x = ph;
    #pragma unroll
    for (int dd=1; dd<64; dd<<=1){ int y = __shfl_up(x, dd, 64); if (t >= dd) x += y; }
    int excl = x - ph;
    int node = (b<<6) + t;
    float dv = rsqrtf((float)(v + 1));
    if (node < N_N){
      sd[node] = make_int2(b*CAP + excl, ph);          // padded count
      dinv[node] = dv;
    }
    sdv[t] = dv;
    lcur[t] = b*CAP + excl;
    for (int j=v; j<ph; j++) ssrc[b*CAP + excl + j] = N_N;   // sentinel pad
  }
  __syncthreads();
  for (int j=t; j<cnt; j+=256){
    unsigned int p = P[j];
    int pos = atomicAdd(&lcur[p & 63], 1);
    ssrc[pos] = (int)(p >> 16);
  }

  // ---- preprocess MLP phase ----
  int row0 = b*64;
  for (int j=t; j<2048; j+=256) ((f4*)Bs)[j] = ((const f4*)W)[j];
  for (int j=t; j<1024; j+=256){
    int r = j>>4, c4 = j&15;
    int gr = row0 + r;
    f4 a = {0.f,0.f,0.f,0.f};
    if (gr < N_N){
      f4 e0 = ((const f4*)emb)[gr*16 + c4];
      f4 p0 = ((const f4*)pose)[gr*16 + c4];
      a.x = e0.x+p0.x; a.y = e0.y+p0.y; a.z = e0.z+p0.z; a.w = e0.w+p0.w;
    }
    ((f4*)As)[j] = a;
  }
  __syncthreads();
  int cg = t&31, rg = t>>5;
  float acc[8][4] = {};
  for (int k=0;k<64;k++){
    f4 bb = ((f4*)Bs)[k*32 + cg];
    #pragma unroll
    for (int i=0;i<8;i++){
      float a = As[(rg*8+i)*64 + k];
      acc[i][0] = fmaf(a,bb.x,acc[i][0]); acc[i][1] = fmaf(a,bb.y,acc[i][1]);
      acc[i][2] = fmaf(a,bb.z,acc[i][2]); acc[i][3] = fmaf(a,bb.w,acc[i][3]);
    }
  }
  f4 bb = ((const f4*)bias)[cg];
  for (int i=0;i<8;i++){
    int gr = row0 + rg*8 + i;
    if (gr < N_N){
      float dv = sdv[rg*8 + i];
      ushort4 o;
      o.x = f2b(fmaxf(acc[i][0]+bb.x, 0.f) * dv);
      o.y = f2b(fmaxf(acc[i][1]+bb.y, 0.f) * dv);
      o.z = f2b(fmaxf(acc[i][2]+bb.z, 0.f) * dv);
      o.w = f2b(fmaxf(acc[i][3]+bb.w, 0.f) * dv);
      *(ushort4*)&out[gr*128 + cg*4] = o;
    }
  }
}

#define CONS4(m) { \
  float2 p0_=b2f2(m.x), p1_=b2f2(m.y), p2_=b2f2(m.z), p3_=b2f2(m.w); \
  A0.x+=p0_.x; A0.y+=p0_.y; A1.x+=p1_.x; A1.y+=p1_.y; \
  A2.x+=p2_.x; A2.y+=p2_.y; A3.x+=p3_.x; A3.y+=p3_.y; }

// ---------------- fused GCN layer: group-per-node 16B-lane gather (8 rows in flight) -> MFMA -> epilogue ----------------
// do_pool=0: write outp (bf16, optionally *dinv).  do_pool=1: block-reduce relu rows into gsum (no store).
__global__ __launch_bounds__(256) void k_layer(const unsigned int* __restrict__ tin,  // [N_N+1][64] dwords
    const int2* __restrict__ sd, const int* __restrict__ ssrc, const float* __restrict__ dinv,
    const unsigned short* __restrict__ Wt, const float* __restrict__ bias,
    unsigned short* __restrict__ outp, int scale_out,
    int do_pool, const int* __restrict__ batch, float* __restrict__ gsum){
  __shared__ unsigned int ts[16*64];   // 16 x 128 bf16, 16B-chunk XOR swizzled
  __shared__ float ps[16][128];        // pool staging (f32)
  __shared__ float sdvs[16];
  __shared__ int sbat[16];
  int t = threadIdx.x;
  int wid = t >> 6, l = t & 63;
  int g = l >> 4, j = l & 15;          // group (node), 16B slot
  int tile0 = blockIdx.x * 16;
  int r = wid*4 + g;                   // row in tile
  int v = tile0 + r;
  const uint4* tin4 = (const uint4*)tin;   // rows of 16 x 16B

  int2 e = sd[v];
  int sg = e.x, pc = e.y;              // 16B-aligned start, 8-padded count
  float dv = dinv[v];

  // self row init
  uint4 sf = tin4[v*16 + j];
  float2 A0 = b2f2(sf.x), A1 = b2f2(sf.y), A2 = b2f2(sf.z), A3 = b2f2(sf.w);

  // 1-deep pipelined edge loop: 8 edges (8 rows) per iteration
  if (pc > 0){
    int4 ua = *(const int4*)(ssrc + sg);
    int4 ub = *(const int4*)(ssrc + sg + 4);
    uint4 m0 = tin4[ua.x*16 + j];
    uint4 m1 = tin4[ua.y*16 + j];
    uint4 m2 = tin4[ua.z*16 + j];
    uint4 m3 = tin4[ua.w*16 + j];
    uint4 m4 = tin4[ub.x*16 + j];
    uint4 m5 = tin4[ub.y*16 + j];
    uint4 m6 = tin4[ub.z*16 + j];
    uint4 m7 = tin4[ub.w*16 + j];
    for (int k=8; k<pc; k+=8){
      int4 va = *(const int4*)(ssrc + sg + k);
      int4 vb = *(const int4*)(ssrc + sg + k + 4);
      uint4 n0 = tin4[va.x*16 + j];
      uint4 n1 = tin4[va.y*16 + j];
      uint4 n2 = tin4[va.z*16 + j];
      uint4 n3 = tin4[va.w*16 + j];
      uint4 n4 = tin4[vb.x*16 + j];
      uint4 n5 = tin4[vb.y*16 + j];
      uint4 n6 = tin4[vb.z*16 + j];
      uint4 n7 = tin4[vb.w*16 + j];
      CONS4(m0) CONS4(m1) CONS4(m2) CONS4(m3)
      CONS4(m4) CONS4(m5) CONS4(m6) CONS4(m7)
      m0=n0; m1=n1; m2=n2; m3=n3; m4=n4; m5=n5; m6=n6; m7=n7;
    }
    CONS4(m0) CONS4(m1) CONS4(m2) CONS4(m3)
    CONS4(m4) CONS4(m5) CONS4(m6) CONS4(m7)
  }

  // stage into LDS (swizzled 16B chunks), scaled by dinv
  if (j == 0) sdvs[r] = dv;
  if (j == 1) sbat[r] = batch[v];
  {
    uint4 q;
    q.x = (unsigned int)f2b(dv*A0.x) | ((unsigned int)f2b(dv*A0.y) << 16);
    q.y = (unsigned int)f2b(dv*A1.x) | ((unsigned int)f2b(dv*A1.y) << 16);
    q.z = (unsigned int)f2b(dv*A2.x) | ((unsigned int)f2b(dv*A2.y) << 16);
    q.w = (unsigned int)f2b(dv*A3.x) | ((unsigned int)f2b(dv*A3.y) << 16);
    *(uint4*)&ts[r*64 + ((j ^ (r&7))<<2)] = q;
  }
  __syncthreads();

  // MFMA: wave wid owns output cols wid*32 .. +31 (2 n-frags), all 16 rows
  int lr = l & 15, kg = l >> 4;
  f32x4 m0 = {0.f,0.f,0.f,0.f}, m1 = {0.f,0.f,0.f,0.f};
  int col0 = wid*32 + lr, col1 = col0 + 16;
  #pragma unroll
  for (int ks=0; ks<4; ks++){
    bf16x8 a = *(bf16x8*)&ts[lr*64 + ((((ks<<2)+kg) ^ (lr&7))<<2)];
    bf16x8 w0 = *(const bf16x8*)&Wt[col0*128 + ks*32 + kg*8];
    bf16x8 w1 = *(const bf16x8*)&Wt[col1*128 + ks*32 + kg*8];
    m0 = __builtin_amdgcn_mfma_f32_16x16x32_bf16(a, w0, m0, 0, 0, 0);
    m1 = __builtin_amdgcn_mfma_f32_16x16x32_bf16(a, w1, m1, 0, 0, 0);
  }
  float bv0 = bias[col0], bv1 = bias[col1];
  if (!do_pool){
    #pragma unroll
    for (int r4=0; r4<4; r4++){
      int row = kg*4 + r4;               // C layout: row = (lane>>4)*4 + reg
      int vv = tile0 + row;
      float dvo = scale_out ? sdvs[row] : 1.f;
      outp[vv*128 + col0] = f2b(fmaxf(m0[r4]+bv0, 0.f) * dvo);
      outp[vv*128 + col1] = f2b(fmaxf(m1[r4]+bv1, 0.f) * dvo);
    }
  } else {
    #pragma unroll
    for (int r4=0; r4<4; r4++){
      int row = kg*4 + r4;
      ps[row][col0] = fmaxf(m0[r4]+bv0, 0.f);
      ps[row][col1] = fmaxf(m1[r4]+bv1, 0.f);
    }
    __syncthreads();
    if (sbat[0] == sbat[15]){
      // common case: whole tile in one graph -> one atomic per column
      if (t < 128){
        float s = 0.f;
        #pragma unroll
        for (int rr=0; rr<16; rr++) s += ps[rr][t];
        atomicAdd(&gsum[sbat[0]*128 + t], s);
      }
    } else {
      // boundary tile: segmented flush (batch sorted)
      int col = t & 127, half = t >> 7;
      int base = half*8;
      float s = 0.f; int cb = sbat[base];
      #pragma unroll
      for (int rr=0; rr<8; rr++){
        int bb = sbat[base+rr];
        if (bb != cb){ atomicAdd(&gsum[cb*128+col], s); s = 0.f; cb = bb; }
        s += ps[base+rr][col];
      }
      atomicAdd(&gsum[cb*128+col], s);
    }
  }
}

// ---------------- head MLP (128->64->32, relu both) ----------------
__global__ __launch_bounds__(64) void k_head(const float* __restrict__ gsum, const float* __restrict__ gcnt,
    const float* __restrict__ W1, const float* __restrict__ b1,
    const float* __restrict__ W2, const float* __restrict__ b2, float* __restrict__ out){
  __shared__ float pooled[128];
  __shared__ float h1[64];
  int g = blockIdx.x, t = threadIdx.x;
  float cnt = fmaxf(gcnt[g], 1.f);
  pooled[t]      = gsum[g*128 + t] / cnt;
  pooled[t + 64] = gsum[g*128 + 64 + t] / cnt;
  __syncthreads();
  float a = b1[t];
  for (int k=0; k<128; k++) a = fmaf(pooled[k], W1[k*64 + t], a);
  h1[t] = fmaxf(a, 0.f);
  __syncthreads();
  if (t < 32){
    float o = b2[t];
    for (int k=0; k<64; k++) o = fmaf(h1[k], W2[k*32 + t], o);
    out[g*32 + t] = fmaxf(o, 0.f);
  }
}

extern "C" void kernel_launch(void* const* d_in, const int* in_sizes, int n_in,
                              void* d_out, int out_size, void* d_ws, size_t ws_size,
                              hipStream_t stream){
  const float* emb  = (const float*)d_in[0];
  const float* pose = (const float*)d_in[1];
  const int*   ei   = (const int*)d_in[2];
  const int*   batch= (const int*)d_in[3];
  const float* Wpre = (const float*)d_in[4];
  const float* bpre = (const float*)d_in[5];
  const float* Wg1  = (const float*)d_in[6];
  const float* bg1  = (const float*)d_in[7];
  const float* Wg2  = (const float*)d_in[8];
  const float* bg2  = (const float*)d_in[9];
  const float* Wh1  = (const float*)d_in[10];
  const float* bh1  = (const float*)d_in[11];
  const float* Wh2  = (const float*)d_in[12];
  const float* bh2  = (const float*)d_in[13];
  float* out = (float*)d_out;

  char* ws = (char*)d_ws;
  unsigned short* xb0 = (unsigned short*)(ws + 0);          // 12,800,256 ((N_N+1) rows)
  unsigned short* xb1 = (unsigned short*)(ws + 12800256);   // 12,800,256
  unsigned short* Wt1 = (unsigned short*)(ws + 25600512);   // 32,768
  unsigned short* Wt2 = (unsigned short*)(ws + 25633280);   // 32,768
  int2*  sd   = (int2*) (ws + 25666048);   // 400,000
  float* dinv = (float*)(ws + 26066048);   // 200,000
  int*   ssrc = (int*)  (ws + 26266048);   // NBKT*CAP*4 = 4,804,608
  unsigned int* bins = (unsigned int*)(ws + 31070656);   // 4,804,608
  // contiguous zero region: bcnt | gsum | gcnt
  int*   bcnt = (int*)  (ws + 35875264);   // 3,136
  float* gsum = (float*)(ws + 35878400);   // 65,536
  float* gcnt = (float*)(ws + 35943936);   // 512

  const int ZN = (3136 + 65536 + 512) / 4;   // 17,296 ints
  const int ZB = (ZN + 255)/256;             // 68 blocks

  k_init<<<128 + ZB + 1, 256, 0, stream>>>(Wg1, Wg2, Wt1, Wt2, bcnt, ZN,
                                           (unsigned int*)xb0, (unsigned int*)xb1);

  k_bin<<<BINB, 512, 0, stream>>>(ei, bcnt, bins, batch, gcnt);
  k_csrpre<<<NBKT, 256, 0, stream>>>(bins, bcnt, sd, dinv, ssrc,
                                     emb, pose, Wpre, bpre, xb0);                 // CSR + x1~ -> xb0

  k_layer<<<N_N/16, 256, 0, stream>>>((const unsigned int*)xb0, sd, ssrc, dinv,
                                      Wt1, bg1, xb1, 1, 0, batch, gsum);          // x2~ -> xb1
  k_layer<<<N_N/16, 256, 0, stream>>>((const unsigned int*)xb1, sd, ssrc, dinv,
                                      Wt2, bg2, xb0, 0, 1, batch, gsum);          // x3 -> pool(gsum)

  k_head<<<NG, 64, 0, stream>>>(gsum, gcnt, Wh1, bh1, Wh2, bh2, out);
}

// Round 20
// 130.505 us; speedup vs baseline: 2.1004x; 2.1004x over previous
//
#include <hip/hip_runtime.h>

#define N_N 50000
#define N_E 800000
#define NG  128
#define NBKT 782          // ceil(50000/64) buckets of 64 nodes
#define CAP  1536         // slot capacity per bucket (8-padded mean ~1248, sigma ~37)
#define EPB  4096         // edges per k_bin block
#define BINB 196          // ceil(800000/4096)

typedef float4 f4;
typedef __attribute__((ext_vector_type(8))) short bf16x8;
typedef __attribute__((ext_vector_type(4))) float f32x4;

__device__ __forceinline__ unsigned short f2b(float x){
  unsigned int u = __float_as_uint(x);
  u += 0x7fffu + ((u >> 16) & 1u);
  return (unsigned short)(u >> 16);
}
__device__ __forceinline__ float b2f(unsigned short h){
  return __uint_as_float(((unsigned int)h) << 16);
}
__device__ __forceinline__ float2 b2f2(unsigned int u){
  float2 r;
  r.x = __uint_as_float(u << 16);
  r.y = __uint_as_float(u & 0xffff0000u);
  return r;
}

// ---------------- init: Wt transpose-cast (bid<128) + zero bcnt|gsum (middle) + sentinels (last) ----------------
__global__ __launch_bounds__(256) void k_init(const float* __restrict__ W1, const float* __restrict__ W2,
    unsigned short* __restrict__ Wt1, unsigned short* __restrict__ Wt2,
    int* __restrict__ zp, int n4, unsigned int* __restrict__ x0z, unsigned int* __restrict__ x1z){
  int bid = blockIdx.x, t = threadIdx.x;
  int i = bid*256 + t;
  if (bid < 128){
    const float* W = (i < 16384) ? W1 : W2;
    unsigned short* Wt = (i < 16384) ? Wt1 : Wt2;
    int j = i & 16383;
    int k = j >> 7, n = j & 127;
    Wt[n*128 + k] = f2b(W[k*128 + n]);
  } else if (bid == gridDim.x - 1){
    if (t < 64)       x0z[(size_t)N_N*64 + t] = 0;        // sentinel row of xb0
    else if (t < 128) x1z[(size_t)N_N*64 + (t-64)] = 0;   // sentinel row of xb1
  } else {
    int z = i - 128*256;
    if (z < n4) zp[z] = 0;
  }
}

// ---------------- block-local counting sort into coarse buckets ----------------
__global__ __launch_bounds__(512) void k_bin(const int* __restrict__ ei,
    int* __restrict__ bcnt, unsigned int* __restrict__ bins){
  __shared__ unsigned int sorted[EPB];   // 16 KB
  __shared__ int hist[NBKT];
  __shared__ int lstart[NBKT];
  __shared__ int lcur[NBKT];
  __shared__ int gbase[NBKT];
  __shared__ int segsum[16];
  int t = threadIdx.x;
  int e0 = blockIdx.x * EPB;
  int n = N_E - e0; if (n > EPB) n = EPB;
  for (int i=t; i<NBKT; i+=512) hist[i] = 0;
  __syncthreads();
  for (int i=t; i<n; i+=512){
    int d = ei[N_E + e0 + i];
    atomicAdd(&hist[d>>6], 1);
  }
  __syncthreads();
  int w = t >> 6, lane = t & 63;
  for (int seg = w; seg < 13; seg += 8){
    int idx = seg*64 + lane;
    int v = (idx < NBKT) ? hist[idx] : 0;
    int x = v;
    #pragma unroll
    for (int dd=1; dd<64; dd<<=1){ int y = __shfl_up(x, dd, 64); if (lane >= dd) x += y; }
    if (idx < NBKT) lstart[idx] = x - v;
    if (lane == 63) segsum[seg] = x;
  }
  __syncthreads();
  if (t == 0){ int s=0; for (int j=0;j<13;j++){ int v=segsum[j]; segsum[j]=s; s+=v; } }
  __syncthreads();
  for (int i=t; i<NBKT; i+=512){ int v = lstart[i] + segsum[i>>6]; lstart[i] = v; lcur[i] = v; }
  __syncthreads();
  for (int i=t; i<n; i+=512){
    int s = ei[e0 + i], d = ei[N_E + e0 + i];
    int pos = atomicAdd(&lcur[d>>6], 1);
    sorted[pos] = ((unsigned int)s << 16) | (unsigned int)d;
  }
  __syncthreads();
  for (int i=t; i<NBKT; i+=512) gbase[i] = atomicAdd(&bcnt[i], hist[i]);
  __syncthreads();
  for (int i=t; i<n; i+=512){
    unsigned int item = sorted[i];
    int d = item & 0xffff;
    int b = d >> 6;
    bins[b*CAP + gbase[b] + (i - lstart[b])] = item;
  }
}

// ---------------- fused: per-bucket CSR finalize (8-padded) + preprocess MLP, out = x1*dinv (bf16) ----------------
__global__ __launch_bounds__(256) void k_csrpre(const unsigned int* __restrict__ bins,
    const int* __restrict__ bcnt, int2* __restrict__ sd, float* __restrict__ dinv,
    int* __restrict__ ssrc,
    const float* __restrict__ emb, const float* __restrict__ pose,
    const float* __restrict__ W, const float* __restrict__ bias, unsigned short* __restrict__ out){
  __shared__ float As[64*64];
  __shared__ float Bs[64*128];
  __shared__ int hist[64];
  __shared__ int lcur[64];
  __shared__ float sdv[64];
  __shared__ int cnt_s;
  int b = blockIdx.x, t = threadIdx.x;

  // ---- CSR phase ----
  if (t < 64) hist[t] = 0;
  if (t == 0) cnt_s = bcnt[b];
  __syncthreads();
  int cnt = cnt_s;
  const unsigned int* P = bins + b*CAP;
  for (int j=t; j<cnt; j+=256) atomicAdd(&hist[P[j] & 63], 1);
  __syncthreads();
  if (t < 64){
    int v = hist[t];
    int ph = (v + 7) & ~7;               // padded to multiple of 8
    int x = ph;
    #pragma unroll
    for (int dd=1; dd<64; dd<<=1){ int y = __shfl_up(x, dd, 64); if (t >= dd) x += y; }
    int excl = x - ph;
    int node = (b<<6) + t;
    float dv = rsqrtf((float)(v + 1));
    if (node < N_N){
      sd[node] = make_int2(b*CAP + excl, ph);          // padded count
      dinv[node] = dv;
    }
    sdv[t] = dv;
    lcur[t] = b*CAP + excl;
    for (int j=v; j<ph; j++) ssrc[b*CAP + excl + j] = N_N;   // sentinel pad
  }
  __syncthreads();
  for (int j=t; j<cnt; j+=256){
    unsigned int p = P[j];
    int pos = atomicAdd(&lcur[p & 63], 1);
    ssrc[pos] = (int)(p >> 16);
  }

  // ---- preprocess MLP phase ----
  int row0 = b*64;
  for (int j=t; j<2048; j+=256) ((f4*)Bs)[j] = ((const f4*)W)[j];
  for (int j=t; j<1024; j+=256){
    int r = j>>4, c4 = j&15;
    int gr = row0 + r;
    f4 a = {0.f,0.f,0.f,0.f};
    if (gr < N_N){
      f4 e0 = ((const f4*)emb)[gr*16 + c4];
      f4 p0 = ((const f4*)pose)[gr*16 + c4];
      a.x = e0.x+p0.x; a.y = e0.y+p0.y; a.z = e0.z+p0.z; a.w = e0.w+p0.w;
    }
    ((f4*)As)[j] = a;
  }
  __syncthreads();
  int cg = t&31, rg = t>>5;
  float acc[8][4] = {};
  for (int k=0;k<64;k++){
    f4 bb = ((f4*)Bs)[k*32 + cg];
    #pragma unroll
    for (int i=0;i<8;i++){
      float a = As[(rg*8+i)*64 + k];
      acc[i][0] = fmaf(a,bb.x,acc[i][0]); acc[i][1] = fmaf(a,bb.y,acc[i][1]);
      acc[i][2] = fmaf(a,bb.z,acc[i][2]); acc[i][3] = fmaf(a,bb.w,acc[i][3]);
    }
  }
  f4 bb = ((const f4*)bias)[cg];
  for (int i=0;i<8;i++){
    int gr = row0 + rg*8 + i;
    if (gr < N_N){
      float dv = sdv[rg*8 + i];
      ushort4 o;
      o.x = f2b(fmaxf(acc[i][0]+bb.x, 0.f) * dv);
      o.y = f2b(fmaxf(acc[i][1]+bb.y, 0.f) * dv);
      o.z = f2b(fmaxf(acc[i][2]+bb.z, 0.f) * dv);
      o.w = f2b(fmaxf(acc[i][3]+bb.w, 0.f) * dv);
      *(ushort4*)&out[gr*128 + cg*4] = o;
    }
  }
}

#define CONS4(m) { \
  float2 p0_=b2f2(m.x), p1_=b2f2(m.y), p2_=b2f2(m.z), p3_=b2f2(m.w); \
  A0.x+=p0_.x; A0.y+=p0_.y; A1.x+=p1_.x; A1.y+=p1_.y; \
  A2.x+=p2_.x; A2.y+=p2_.y; A3.x+=p3_.x; A3.y+=p3_.y; }

// ---------------- fused GCN layer: group-per-node 16B-lane gather (8 rows in flight) -> MFMA -> epilogue ----------------
// do_pool=0: write outp (bf16, optionally *dinv).  do_pool=1: block-reduce relu rows into gsum (no store).
__global__ __launch_bounds__(256) void k_layer(const unsigned int* __restrict__ tin,  // [N_N+1][64] dwords
    const int2* __restrict__ sd, const int* __restrict__ ssrc, const float* __restrict__ dinv,
    const unsigned short* __restrict__ Wt, const float* __restrict__ bias,
    unsigned short* __restrict__ outp, int scale_out,
    int do_pool, const int* __restrict__ batch, float* __restrict__ gsum){
  __shared__ unsigned int ts[16*64];   // 16 x 128 bf16, 16B-chunk XOR swizzled
  __shared__ float ps[16][128];        // pool staging (f32)
  __shared__ float sdvs[16];
  __shared__ int sbat[16];
  int t = threadIdx.x;
  int wid = t >> 6, l = t & 63;
  int g = l >> 4, j = l & 15;          // group (node), 16B slot
  int tile0 = blockIdx.x * 16;
  int r = wid*4 + g;                   // row in tile
  int v = tile0 + r;
  const uint4* tin4 = (const uint4*)tin;   // rows of 16 x 16B

  int2 e = sd[v];
  int sg = e.x, pc = e.y;              // 16B-aligned start, 8-padded count
  float dv = dinv[v];

  // self row init
  uint4 sf = tin4[v*16 + j];
  float2 A0 = b2f2(sf.x), A1 = b2f2(sf.y), A2 = b2f2(sf.z), A3 = b2f2(sf.w);

  // 1-deep pipelined edge loop: 8 edges (8 rows) per iteration
  if (pc > 0){
    int4 ua = *(const int4*)(ssrc + sg);
    int4 ub = *(const int4*)(ssrc + sg + 4);
    uint4 m0 = tin4[ua.x*16 + j];
    uint4 m1 = tin4[ua.y*16 + j];
    uint4 m2 = tin4[ua.z*16 + j];
    uint4 m3 = tin4[ua.w*16 + j];
    uint4 m4 = tin4[ub.x*16 + j];
    uint4 m5 = tin4[ub.y*16 + j];
    uint4 m6 = tin4[ub.z*16 + j];
    uint4 m7 = tin4[ub.w*16 + j];
    for (int k=8; k<pc; k+=8){
      int4 va = *(const int4*)(ssrc + sg + k);
      int4 vb = *(const int4*)(ssrc + sg + k + 4);
      uint4 n0 = tin4[va.x*16 + j];
      uint4 n1 = tin4[va.y*16 + j];
      uint4 n2 = tin4[va.z*16 + j];
      uint4 n3 = tin4[va.w*16 + j];
      uint4 n4 = tin4[vb.x*16 + j];
      uint4 n5 = tin4[vb.y*16 + j];
      uint4 n6 = tin4[vb.z*16 + j];
      uint4 n7 = tin4[vb.w*16 + j];
      CONS4(m0) CONS4(m1) CONS4(m2) CONS4(m3)
      CONS4(m4) CONS4(m5) CONS4(m6) CONS4(m7)
      m0=n0; m1=n1; m2=n2; m3=n3; m4=n4; m5=n5; m6=n6; m7=n7;
    }
    CONS4(m0) CONS4(m1) CONS4(m2) CONS4(m3)
    CONS4(m4) CONS4(m5) CONS4(m6) CONS4(m7)
  }

  // stage into LDS (swizzled 16B chunks), scaled by dinv
  if (j == 0) sdvs[r] = dv;
  if (j == 1) sbat[r] = batch[v];
  {
    uint4 q;
    q.x = (unsigned int)f2b(dv*A0.x) | ((unsigned int)f2b(dv*A0.y) << 16);
    q.y = (unsigned int)f2b(dv*A1.x) | ((unsigned int)f2b(dv*A1.y) << 16);
    q.z = (unsigned int)f2b(dv*A2.x) | ((unsigned int)f2b(dv*A2.y) << 16);
    q.w = (unsigned int)f2b(dv*A3.x) | ((unsigned int)f2b(dv*A3.y) << 16);
    *(uint4*)&ts[r*64 + ((j ^ (r&7))<<2)] = q;
  }
  __syncthreads();

  // MFMA: wave wid owns output cols wid*32 .. +31 (2 n-frags), all 16 rows
  int lr = l & 15, kg = l >> 4;
  f32x4 m0 = {0.f,0.f,0.f,0.f}, m1 = {0.f,0.f,0.f,0.f};
  int col0 = wid*32 + lr, col1 = col0 + 16;
  #pragma unroll
  for (int ks=0; ks<4; ks++){
    bf16x8 a = *(bf16x8*)&ts[lr*64 + ((((ks<<2)+kg) ^ (lr&7))<<2)];
    bf16x8 w0 = *(const bf16x8*)&Wt[col0*128 + ks*32 + kg*8];
    bf16x8 w1 = *(const bf16x8*)&Wt[col1*128 + ks*32 + kg*8];
    m0 = __builtin_amdgcn_mfma_f32_16x16x32_bf16(a, w0, m0, 0, 0, 0);
    m1 = __builtin_amdgcn_mfma_f32_16x16x32_bf16(a, w1, m1, 0, 0, 0);
  }
  float bv0 = bias[col0], bv1 = bias[col1];
  if (!do_pool){
    #pragma unroll
    for (int r4=0; r4<4; r4++){
      int row = kg*4 + r4;               // C layout: row = (lane>>4)*4 + reg
      int vv = tile0 + row;
      float dvo = scale_out ? sdvs[row] : 1.f;
      outp[vv*128 + col0] = f2b(fmaxf(m0[r4]+bv0, 0.f) * dvo);
      outp[vv*128 + col1] = f2b(fmaxf(m1[r4]+bv1, 0.f) * dvo);
    }
  } else {
    #pragma unroll
    for (int r4=0; r4<4; r4++){
      int row = kg*4 + r4;
      ps[row][col0] = fmaxf(m0[r4]+bv0, 0.f);
      ps[row][col1] = fmaxf(m1[r4]+bv1, 0.f);
    }
    __syncthreads();
    if (sbat[0] == sbat[15]){
      // common case: whole tile in one graph -> one atomic per column
      if (t < 128){
        float s = 0.f;
        #pragma unroll
        for (int rr=0; rr<16; rr++) s += ps[rr][t];
        atomicAdd(&gsum[sbat[0]*128 + t], s);
      }
    } else {
      // boundary tile: segmented flush (batch sorted)
      int col = t & 127, half = t >> 7;
      int base = half*8;
      float s = 0.f; int cb = sbat[base];
      #pragma unroll
      for (int rr=0; rr<8; rr++){
        int bb = sbat[base+rr];
        if (bb != cb){ atomicAdd(&gsum[cb*128+col], s); s = 0.f; cb = bb; }
        s += ps[base+rr][col];
      }
      atomicAdd(&gsum[cb*128+col], s);
    }
  }
}

// ---------------- head MLP (128->64->32, relu both); graph size via binary search on sorted batch ----------------
__global__ __launch_bounds__(64) void k_head(const float* __restrict__ gsum, const int* __restrict__ batch,
    const float* __restrict__ W1, const float* __restrict__ b1,
    const float* __restrict__ W2, const float* __restrict__ b2, float* __restrict__ out){
  __shared__ float pooled[128];
  __shared__ float h1[64];
  __shared__ float cnt_s;
  int g = blockIdx.x, t = threadIdx.x;
  if (t == 0){
    int lo = 0, hi = N_N;
    while (lo < hi){ int mid = (lo+hi)>>1; if (batch[mid] < g) lo = mid+1; else hi = mid; }
    int start = lo;
    hi = N_N;
    while (lo < hi){ int mid = (lo+hi)>>1; if (batch[mid] < g+1) lo = mid+1; else hi = mid; }
    cnt_s = fmaxf((float)(lo - start), 1.f);
  }
  __syncthreads();
  float cnt = cnt_s;
  pooled[t]      = gsum[g*128 + t] / cnt;
  pooled[t + 64] = gsum[g*128 + 64 + t] / cnt;
  __syncthreads();
  float a = b1[t];
  for (int k=0; k<128; k++) a = fmaf(pooled[k], W1[k*64 + t], a);
  h1[t] = fmaxf(a, 0.f);
  __syncthreads();
  if (t < 32){
    float o = b2[t];
    for (int k=0; k<64; k++) o = fmaf(h1[k], W2[k*32 + t], o);
    out[g*32 + t] = fmaxf(o, 0.f);
  }
}

extern "C" void kernel_launch(void* const* d_in, const int* in_sizes, int n_in,
                              void* d_out, int out_size, void* d_ws, size_t ws_size,
                              hipStream_t stream){
  const float* emb  = (const float*)d_in[0];
  const float* pose = (const float*)d_in[1];
  const int*   ei   = (const int*)d_in[2];
  const int*   batch= (const int*)d_in[3];
  const float* Wpre = (const float*)d_in[4];
  const float* bpre = (const float*)d_in[5];
  const float* Wg1  = (const float*)d_in[6];
  const float* bg1  = (const float*)d_in[7];
  const float* Wg2  = (const float*)d_in[8];
  const float* bg2  = (const float*)d_in[9];
  const float* Wh1  = (const float*)d_in[10];
  const float* bh1  = (const float*)d_in[11];
  const float* Wh2  = (const float*)d_in[12];
  const float* bh2  = (const float*)d_in[13];
  float* out = (float*)d_out;

  char* ws = (char*)d_ws;
  unsigned short* xb0 = (unsigned short*)(ws + 0);          // 12,800,256 ((N_N+1) rows)
  unsigned short* xb1 = (unsigned short*)(ws + 12800256);   // 12,800,256
  unsigned short* Wt1 = (unsigned short*)(ws + 25600512);   // 32,768
  unsigned short* Wt2 = (unsigned short*)(ws + 25633280);   // 32,768
  int2*  sd   = (int2*) (ws + 25666048);   // 400,000
  float* dinv = (float*)(ws + 26066048);   // 200,000
  int*   ssrc = (int*)  (ws + 26266048);   // NBKT*CAP*4 = 4,804,608
  unsigned int* bins = (unsigned int*)(ws + 31070656);   // 4,804,608
  // contiguous zero region: bcnt | gsum
  int*   bcnt = (int*)  (ws + 35875264);   // 3,136
  float* gsum = (float*)(ws + 35878400);   // 65,536

  const int ZN = (3136 + 65536) / 4;   // 17,168 ints
  const int ZB = (ZN + 255)/256;       // 68 blocks

  k_init<<<128 + ZB + 1, 256, 0, stream>>>(Wg1, Wg2, Wt1, Wt2, bcnt, ZN,
                                           (unsigned int*)xb0, (unsigned int*)xb1);

  k_bin<<<BINB, 512, 0, stream>>>(ei, bcnt, bins);
  k_csrpre<<<NBKT, 256, 0, stream>>>(bins, bcnt, sd, dinv, ssrc,
                                     emb, pose, Wpre, bpre, xb0);                 // CSR + x1~ -> xb0

  k_layer<<<N_N/16, 256, 0, stream>>>((const unsigned int*)xb0, sd, ssrc, dinv,
                                      Wt1, bg1, xb1, 1, 0, batch, gsum);          // x2~ -> xb1
  k_layer<<<N_N/16, 256, 0, stream>>>((const unsigned int*)xb1, sd, ssrc, dinv,
                                      Wt2, bg2, xb0, 0, 1, batch, gsum);          // x3 -> pool(gsum)

  k_head<<<NG, 64, 0, stream>>>(gsum, batch, Wh1, bh1, Wh2, bh2, out);
}

// Round 21
// 130.141 us; speedup vs baseline: 2.1063x; 1.0028x over previous
//
#include <hip/hip_runtime.h>

#define N_N 50000
#define N_E 800000
#define NG  128
#define NBKT 782          // ceil(50000/64) buckets of 64 nodes
#define CAP  1536         // slot capacity per bucket (8-padded mean ~1248, sigma ~37)
#define EPB  4096         // edges per k_bin block
#define BINB 196          // ceil(800000/4096)

typedef float4 f4;
typedef __attribute__((ext_vector_type(8))) short bf16x8;
typedef __attribute__((ext_vector_type(4))) float f32x4;

__device__ __forceinline__ unsigned short f2b(float x){
  unsigned int u = __float_as_uint(x);
  u += 0x7fffu + ((u >> 16) & 1u);
  return (unsigned short)(u >> 16);
}
__device__ __forceinline__ float b2f(unsigned short h){
  return __uint_as_float(((unsigned int)h) << 16);
}
__device__ __forceinline__ float2 b2f2(unsigned int u){
  float2 r;
  r.x = __uint_as_float(u << 16);
  r.y = __uint_as_float(u & 0xffff0000u);
  return r;
}

// ---------------- init: Wt transpose-cast (bid<128) + zero bcnt|gsum (middle) + sentinels (last) ----------------
__global__ __launch_bounds__(256) void k_init(const float* __restrict__ W1, const float* __restrict__ W2,
    unsigned short* __restrict__ Wt1, unsigned short* __restrict__ Wt2,
    int* __restrict__ zp, int n4, unsigned int* __restrict__ x0z, unsigned int* __restrict__ x1z){
  int bid = blockIdx.x, t = threadIdx.x;
  int i = bid*256 + t;
  if (bid < 128){
    const float* W = (i < 16384) ? W1 : W2;
    unsigned short* Wt = (i < 16384) ? Wt1 : Wt2;
    int j = i & 16383;
    int k = j >> 7, n = j & 127;
    Wt[n*128 + k] = f2b(W[k*128 + n]);
  } else if (bid == gridDim.x - 1){
    if (t < 64)       x0z[(size_t)N_N*64 + t] = 0;        // sentinel row of xb0
    else if (t < 128) x1z[(size_t)N_N*64 + (t-64)] = 0;   // sentinel row of xb1
  } else {
    int z = i - 128*256;
    if (z < n4) zp[z] = 0;
  }
}

// ---------------- block-local counting sort into coarse buckets ----------------
__global__ __launch_bounds__(512) void k_bin(const int* __restrict__ ei,
    int* __restrict__ bcnt, unsigned int* __restrict__ bins){
  __shared__ unsigned int sorted[EPB];   // 16 KB
  __shared__ int hist[NBKT];
  __shared__ int lstart[NBKT];
  __shared__ int lcur[NBKT];
  __shared__ int gbase[NBKT];
  __shared__ int segsum[16];
  int t = threadIdx.x;
  int e0 = blockIdx.x * EPB;
  int n = N_E - e0; if (n > EPB) n = EPB;
  for (int i=t; i<NBKT; i+=512) hist[i] = 0;
  __syncthreads();
  for (int i=t; i<n; i+=512){
    int d = ei[N_E + e0 + i];
    atomicAdd(&hist[d>>6], 1);
  }
  __syncthreads();
  int w = t >> 6, lane = t & 63;
  for (int seg = w; seg < 13; seg += 8){
    int idx = seg*64 + lane;
    int v = (idx < NBKT) ? hist[idx] : 0;
    int x = v;
    #pragma unroll
    for (int dd=1; dd<64; dd<<=1){ int y = __shfl_up(x, dd, 64); if (lane >= dd) x += y; }
    if (idx < NBKT) lstart[idx] = x - v;
    if (lane == 63) segsum[seg] = x;
  }
  __syncthreads();
  if (t == 0){ int s=0; for (int j=0;j<13;j++){ int v=segsum[j]; segsum[j]=s; s+=v; } }
  __syncthreads();
  for (int i=t; i<NBKT; i+=512){ int v = lstart[i] + segsum[i>>6]; lstart[i] = v; lcur[i] = v; }
  __syncthreads();
  for (int i=t; i<n; i+=512){
    int s = ei[e0 + i], d = ei[N_E + e0 + i];
    int pos = atomicAdd(&lcur[d>>6], 1);
    sorted[pos] = ((unsigned int)s << 16) | (unsigned int)d;
  }
  __syncthreads();
  for (int i=t; i<NBKT; i+=512) gbase[i] = atomicAdd(&bcnt[i], hist[i]);
  __syncthreads();
  for (int i=t; i<n; i+=512){
    unsigned int item = sorted[i];
    int d = item & 0xffff;
    int b = d >> 6;
    bins[b*CAP + gbase[b] + (i - lstart[b])] = item;
  }
}

// ---------------- fused: per-bucket CSR finalize (8-padded) + preprocess MLP, out = x1*dinv (bf16) ----------------
__global__ __launch_bounds__(256) void k_csrpre(const unsigned int* __restrict__ bins,
    const int* __restrict__ bcnt, int2* __restrict__ sd, float* __restrict__ dinv,
    int* __restrict__ ssrc,
    const float* __restrict__ emb, const float* __restrict__ pose,
    const float* __restrict__ W, const float* __restrict__ bias, unsigned short* __restrict__ out){
  __shared__ float As[64*64];
  __shared__ float Bs[64*128];
  __shared__ int hist[64];
  __shared__ int lcur[64];
  __shared__ float sdv[64];
  __shared__ int cnt_s;
  int b = blockIdx.x, t = threadIdx.x;

  // ---- CSR phase ----
  if (t < 64) hist[t] = 0;
  if (t == 0) cnt_s = bcnt[b];
  __syncthreads();
  int cnt = cnt_s;
  const unsigned int* P = bins + b*CAP;
  for (int j=t; j<cnt; j+=256) atomicAdd(&hist[P[j] & 63], 1);
  __syncthreads();
  if (t < 64){
    int v = hist[t];
    int ph = (v + 7) & ~7;               // padded to multiple of 8
    int x = ph;
    #pragma unroll
    for (int dd=1; dd<64; dd<<=1){ int y = __shfl_up(x, dd, 64); if (t >= dd) x += y; }
    int excl = x - ph;
    int node = (b<<6) + t;
    float dv = rsqrtf((float)(v + 1));
    if (node < N_N){
      sd[node] = make_int2(b*CAP + excl, ph);          // padded count
      dinv[node] = dv;
    }
    sdv[t] = dv;
    lcur[t] = b*CAP + excl;
    for (int j=v; j<ph; j++) ssrc[b*CAP + excl + j] = N_N;   // sentinel pad
  }
  __syncthreads();
  for (int j=t; j<cnt; j+=256){
    unsigned int p = P[j];
    int pos = atomicAdd(&lcur[p & 63], 1);
    ssrc[pos] = (int)(p >> 16);
  }

  // ---- preprocess MLP phase ----
  int row0 = b*64;
  for (int j=t; j<2048; j+=256) ((f4*)Bs)[j] = ((const f4*)W)[j];
  for (int j=t; j<1024; j+=256){
    int r = j>>4, c4 = j&15;
    int gr = row0 + r;
    f4 a = {0.f,0.f,0.f,0.f};
    if (gr < N_N){
      f4 e0 = ((const f4*)emb)[gr*16 + c4];
      f4 p0 = ((const f4*)pose)[gr*16 + c4];
      a.x = e0.x+p0.x; a.y = e0.y+p0.y; a.z = e0.z+p0.z; a.w = e0.w+p0.w;
    }
    ((f4*)As)[j] = a;
  }
  __syncthreads();
  int cg = t&31, rg = t>>5;
  float acc[8][4] = {};
  for (int k=0;k<64;k++){
    f4 bb = ((f4*)Bs)[k*32 + cg];
    #pragma unroll
    for (int i=0;i<8;i++){
      float a = As[(rg*8+i)*64 + k];
      acc[i][0] = fmaf(a,bb.x,acc[i][0]); acc[i][1] = fmaf(a,bb.y,acc[i][1]);
      acc[i][2] = fmaf(a,bb.z,acc[i][2]); acc[i][3] = fmaf(a,bb.w,acc[i][3]);
    }
  }
  f4 bb = ((const f4*)bias)[cg];
  for (int i=0;i<8;i++){
    int gr = row0 + rg*8 + i;
    if (gr < N_N){
      float dv = sdv[rg*8 + i];
      ushort4 o;
      o.x = f2b(fmaxf(acc[i][0]+bb.x, 0.f) * dv);
      o.y = f2b(fmaxf(acc[i][1]+bb.y, 0.f) * dv);
      o.z = f2b(fmaxf(acc[i][2]+bb.z, 0.f) * dv);
      o.w = f2b(fmaxf(acc[i][3]+bb.w, 0.f) * dv);
      *(ushort4*)&out[gr*128 + cg*4] = o;
    }
  }
}

#define CONS4(m) { \
  float2 p0_=b2f2(m.x), p1_=b2f2(m.y), p2_=b2f2(m.z), p3_=b2f2(m.w); \
  A0.x+=p0_.x; A0.y+=p0_.y; A1.x+=p1_.x; A1.y+=p1_.y; \
  A2.x+=p2_.x; A2.y+=p2_.y; A3.x+=p3_.x; A3.y+=p3_.y; }

// ---------------- fused GCN layer: group-per-node gather (8 rows in flight, idx prefetched 1 iter ahead) ----------------
// DO_POOL=0: write outp (bf16 * dinv if scale_out). DO_POOL=1: block-reduce relu rows into gsum (no store).
template<int DO_POOL>
__global__ __launch_bounds__(256) void k_layer(const unsigned int* __restrict__ tin,  // [N_N+1][64] dwords
    const int2* __restrict__ sd, const int* __restrict__ ssrc, const float* __restrict__ dinv,
    const unsigned short* __restrict__ Wt, const float* __restrict__ bias,
    unsigned short* __restrict__ outp, int scale_out,
    const int* __restrict__ batch, float* __restrict__ gsum){
  __shared__ __align__(16) float smem[DO_POOL ? 16*128 : 16*64];  // pool: ps(8KB) unions ts(4KB)
  unsigned int* ts = (unsigned int*)smem;
  __shared__ float sdvs[16];
  __shared__ int sbat[16];
  int t = threadIdx.x;
  int wid = t >> 6, l = t & 63;
  int g = l >> 4, j = l & 15;          // group (node), 16B slot
  int tile0 = blockIdx.x * 16;
  int r = wid*4 + g;                   // row in tile
  int v = tile0 + r;
  const uint4* tin4 = (const uint4*)tin;   // rows of 16 x 16B

  int2 e = sd[v];
  int sg = e.x, pc = e.y;              // 16B-aligned start, 8-padded count
  float dv = dinv[v];

  // self row init
  uint4 sf = tin4[v*16 + j];
  float2 A0 = b2f2(sf.x), A1 = b2f2(sf.y), A2 = b2f2(sf.z), A3 = b2f2(sf.w);

  // gather loop: 8 rows per iteration; next iteration's indices prefetched during current gathers
  if (pc > 0){
    int4 ia = *(const int4*)(ssrc + sg);
    int4 ib = *(const int4*)(ssrc + sg + 4);
    uint4 m0 = tin4[ia.x*16 + j];
    uint4 m1 = tin4[ia.y*16 + j];
    uint4 m2 = tin4[ia.z*16 + j];
    uint4 m3 = tin4[ia.w*16 + j];
    uint4 m4 = tin4[ib.x*16 + j];
    uint4 m5 = tin4[ib.y*16 + j];
    uint4 m6 = tin4[ib.z*16 + j];
    uint4 m7 = tin4[ib.w*16 + j];
    int4 pa, pb;
    if (pc > 8){ pa = *(const int4*)(ssrc + sg + 8); pb = *(const int4*)(ssrc + sg + 12); }
    for (int k=8; k<pc; k+=8){
      uint4 n0 = tin4[pa.x*16 + j];
      uint4 n1 = tin4[pa.y*16 + j];
      uint4 n2 = tin4[pa.z*16 + j];
      uint4 n3 = tin4[pa.w*16 + j];
      uint4 n4 = tin4[pb.x*16 + j];
      uint4 n5 = tin4[pb.y*16 + j];
      uint4 n6 = tin4[pb.z*16 + j];
      uint4 n7 = tin4[pb.w*16 + j];
      if (k + 8 < pc){
        pa = *(const int4*)(ssrc + sg + k + 8);
        pb = *(const int4*)(ssrc + sg + k + 12);
      }
      CONS4(m0) CONS4(m1) CONS4(m2) CONS4(m3)
      CONS4(m4) CONS4(m5) CONS4(m6) CONS4(m7)
      m0=n0; m1=n1; m2=n2; m3=n3; m4=n4; m5=n5; m6=n6; m7=n7;
    }
    CONS4(m0) CONS4(m1) CONS4(m2) CONS4(m3)
    CONS4(m4) CONS4(m5) CONS4(m6) CONS4(m7)
  }

  // stage into LDS (swizzled 16B chunks), scaled by dinv
  if (j == 0) sdvs[r] = dv;
  if (DO_POOL && j == 1) sbat[r] = batch[v];
  {
    uint4 q;
    q.x = (unsigned int)f2b(dv*A0.x) | ((unsigned int)f2b(dv*A0.y) << 16);
    q.y = (unsigned int)f2b(dv*A1.x) | ((unsigned int)f2b(dv*A1.y) << 16);
    q.z = (unsigned int)f2b(dv*A2.x) | ((unsigned int)f2b(dv*A2.y) << 16);
    q.w = (unsigned int)f2b(dv*A3.x) | ((unsigned int)f2b(dv*A3.y) << 16);
    *(uint4*)&ts[r*64 + ((j ^ (r&7))<<2)] = q;
  }
  __syncthreads();

  // MFMA: wave wid owns output cols wid*32 .. +31 (2 n-frags), all 16 rows
  int lr = l & 15, kg = l >> 4;
  f32x4 m0 = {0.f,0.f,0.f,0.f}, m1 = {0.f,0.f,0.f,0.f};
  int col0 = wid*32 + lr, col1 = col0 + 16;
  #pragma unroll
  for (int ks=0; ks<4; ks++){
    bf16x8 a = *(bf16x8*)&ts[lr*64 + ((((ks<<2)+kg) ^ (lr&7))<<2)];
    bf16x8 w0 = *(const bf16x8*)&Wt[col0*128 + ks*32 + kg*8];
    bf16x8 w1 = *(const bf16x8*)&Wt[col1*128 + ks*32 + kg*8];
    m0 = __builtin_amdgcn_mfma_f32_16x16x32_bf16(a, w0, m0, 0, 0, 0);
    m1 = __builtin_amdgcn_mfma_f32_16x16x32_bf16(a, w1, m1, 0, 0, 0);
  }
  float bv0 = bias[col0], bv1 = bias[col1];
  if (!DO_POOL){
    #pragma unroll
    for (int r4=0; r4<4; r4++){
      int row = kg*4 + r4;               // C layout: row = (lane>>4)*4 + reg
      int vv = tile0 + row;
      float dvo = scale_out ? sdvs[row] : 1.f;
      outp[vv*128 + col0] = f2b(fmaxf(m0[r4]+bv0, 0.f) * dvo);
      outp[vv*128 + col1] = f2b(fmaxf(m1[r4]+bv1, 0.f) * dvo);
    }
  } else {
    __syncthreads();                     // all ts reads done before ps overwrites smem
    #pragma unroll
    for (int r4=0; r4<4; r4++){
      int row = kg*4 + r4;
      smem[row*128 + col0] = fmaxf(m0[r4]+bv0, 0.f);
      smem[row*128 + col1] = fmaxf(m1[r4]+bv1, 0.f);
    }
    __syncthreads();
    if (sbat[0] == sbat[15]){
      // common case: whole tile in one graph -> one atomic per column
      if (t < 128){
        float s = 0.f;
        #pragma unroll
        for (int rr=0; rr<16; rr++) s += smem[rr*128 + t];
        atomicAdd(&gsum[sbat[0]*128 + t], s);
      }
    } else {
      // boundary tile: segmented flush (batch sorted)
      int col = t & 127, half = t >> 7;
      int base = half*8;
      float s = 0.f; int cb = sbat[base];
      #pragma unroll
      for (int rr=0; rr<8; rr++){
        int bb = sbat[base+rr];
        if (bb != cb){ atomicAdd(&gsum[cb*128+col], s); s = 0.f; cb = bb; }
        s += smem[(base+rr)*128 + col];
      }
      atomicAdd(&gsum[cb*128+col], s);
    }
  }
}

// ---------------- head MLP (128->64->32, relu both); graph size via binary search on sorted batch ----------------
__global__ __launch_bounds__(64) void k_head(const float* __restrict__ gsum, const int* __restrict__ batch,
    const float* __restrict__ W1, const float* __restrict__ b1,
    const float* __restrict__ W2, const float* __restrict__ b2, float* __restrict__ out){
  __shared__ float pooled[128];
  __shared__ float h1[64];
  __shared__ float cnt_s;
  int g = blockIdx.x, t = threadIdx.x;
  if (t == 0){
    int lo = 0, hi = N_N;
    while (lo < hi){ int mid = (lo+hi)>>1; if (batch[mid] < g) lo = mid+1; else hi = mid; }
    int start = lo;
    hi = N_N;
    while (lo < hi){ int mid = (lo+hi)>>1; if (batch[mid] < g+1) lo = mid+1; else hi = mid; }
    cnt_s = fmaxf((float)(lo - start), 1.f);
  }
  __syncthreads();
  float cnt = cnt_s;
  pooled[t]      = gsum[g*128 + t] / cnt;
  pooled[t + 64] = gsum[g*128 + 64 + t] / cnt;
  __syncthreads();
  float a = b1[t];
  for (int k=0; k<128; k++) a = fmaf(pooled[k], W1[k*64 + t], a);
  h1[t] = fmaxf(a, 0.f);
  __syncthreads();
  if (t < 32){
    float o = b2[t];
    for (int k=0; k<64; k++) o = fmaf(h1[k], W2[k*32 + t], o);
    out[g*32 + t] = fmaxf(o, 0.f);
  }
}

extern "C" void kernel_launch(void* const* d_in, const int* in_sizes, int n_in,
                              void* d_out, int out_size, void* d_ws, size_t ws_size,
                              hipStream_t stream){
  const float* emb  = (const float*)d_in[0];
  const float* pose = (const float*)d_in[1];
  const int*   ei   = (const int*)d_in[2];
  const int*   batch= (const int*)d_in[3];
  const float* Wpre = (const float*)d_in[4];
  const float* bpre = (const float*)d_in[5];
  const float* Wg1  = (const float*)d_in[6];
  const float* bg1  = (const float*)d_in[7];
  const float* Wg2  = (const float*)d_in[8];
  const float* bg2  = (const float*)d_in[9];
  const float* Wh1  = (const float*)d_in[10];
  const float* bh1  = (const float*)d_in[11];
  const float* Wh2  = (const float*)d_in[12];
  const float* bh2  = (const float*)d_in[13];
  float* out = (float*)d_out;

  char* ws = (char*)d_ws;
  unsigned short* xb0 = (unsigned short*)(ws + 0);          // 12,800,256 ((N_N+1) rows)
  unsigned short* xb1 = (unsigned short*)(ws + 12800256);   // 12,800,256
  unsigned short* Wt1 = (unsigned short*)(ws + 25600512);   // 32,768
  unsigned short* Wt2 = (unsigned short*)(ws + 25633280);   // 32,768
  int2*  sd   = (int2*) (ws + 25666048);   // 400,000
  float* dinv = (float*)(ws + 26066048);   // 200,000
  int*   ssrc = (int*)  (ws + 26266048);   // NBKT*CAP*4 = 4,804,608
  unsigned int* bins = (unsigned int*)(ws + 31070656);   // 4,804,608
  // contiguous zero region: bcnt | gsum
  int*   bcnt = (int*)  (ws + 35875264);   // 3,136
  float* gsum = (float*)(ws + 35878400);   // 65,536

  const int ZN = (3136 + 65536) / 4;   // 17,168 ints
  const int ZB = (ZN + 255)/256;       // 68 blocks

  k_init<<<128 + ZB + 1, 256, 0, stream>>>(Wg1, Wg2, Wt1, Wt2, bcnt, ZN,
                                           (unsigned int*)xb0, (unsigned int*)xb1);

  k_bin<<<BINB, 512, 0, stream>>>(ei, bcnt, bins);
  k_csrpre<<<NBKT, 256, 0, stream>>>(bins, bcnt, sd, dinv, ssrc,
                                     emb, pose, Wpre, bpre, xb0);                 // CSR + x1~ -> xb0

  k_layer<0><<<N_N/16, 256, 0, stream>>>((const unsigned int*)xb0, sd, ssrc, dinv,
                                         Wt1, bg1, xb1, 1, batch, gsum);          // x2~ -> xb1
  k_layer<1><<<N_N/16, 256, 0, stream>>>((const unsigned int*)xb1, sd, ssrc, dinv,
                                         Wt2, bg2, xb0, 0, batch, gsum);          // x3 -> pool(gsum)

  k_head<<<NG, 64, 0, stream>>>(gsum, batch, Wh1, bh1, Wh2, bh2, out);
}